// Round 2
// baseline (4271.266 us; speedup 1.0000x reference)
//
#include <hip/hip_runtime.h>
#include <hip/hip_bf16.h>
#include <cstdint>
#include <cstddef>

// SlabAttention on MI355X (gfx950).
// Stage 1: qkv = x @ qkv_w^T  (bf16 MFMA 16x16x32, 128x128 tiles)
//          epilogue: q=relu(q); k=relu(k+pos); scatter to (BH,N,32) bf16
// Stage 2: kv_part[bh,4] = k^T v partials (NO atomics), ksum_part likewise
// Stage 3: out_pre = (q@kv)*z + dwconv5x5(v) + b,  z = 1/(q.ksum+eps) -> (B,N,C) bf16
//          (sums the 4 kv/ksum partials while loading them to LDS)
// Stage 4: out = out_pre @ proj_w^T + proj_b  (bf16 MFMA, fp32 out)

typedef __bf16 bf16;
typedef __attribute__((ext_vector_type(8))) __bf16 bf16x8;
typedef __attribute__((ext_vector_type(4))) __bf16 bf16x4;
typedef __attribute__((ext_vector_type(4))) float f32x4;

#define NHEADS 12
#define HD 32
#define BATCH 16
#define SEQ 4096
#define CDIM 384
#define BHN (BATCH*NHEADS)   // 192
#define KVPARTS 4

// ---------------------------------------------------------------- K0: convert
__global__ void convert_w(const float* __restrict__ qkvw, const float* __restrict__ projw,
                          bf16* __restrict__ qkvw_b, bf16* __restrict__ projw_b) {
    int i = blockIdx.x * 256 + threadIdx.x;
    int stride = gridDim.x * 256;
    const int nq = 3 * CDIM * CDIM;      // 442368
    const int np = CDIM * CDIM;          // 147456
    for (int idx = i; idx < nq; idx += stride) qkvw_b[idx] = (bf16)qkvw[idx];
    for (int idx = i; idx < np; idx += stride) projw_b[idx] = (bf16)projw[idx];
}

// ---------------------------------------------------------------- K1: qkv GEMM
// A = x fp32 (65536 x 384), B = qkv_w bf16 (1152 x 384) both K-contiguous.
__global__ __launch_bounds__(256, 2)
void gemm_qkv(const float* __restrict__ X, const bf16* __restrict__ Wb,
              const float* __restrict__ pos,
              bf16* __restrict__ qh, bf16* __restrict__ kh, bf16* __restrict__ vh) {
    __shared__ bf16 As[128 * 64];
    __shared__ bf16 Bs[128 * 64];
    const int tid  = threadIdx.x;
    const int lane = tid & 63;
    const int wid  = tid >> 6;
    const int m0   = blockIdx.y * 128;
    const int n0   = blockIdx.x * 128;
    const int wm   = (wid & 1) * 64;
    const int wn   = (wid >> 1) * 64;
    const int lr   = lane & 15;   // fragment row/col
    const int lq   = lane >> 4;   // quad

    f32x4 acc[4][4] = {};

    for (int k0 = 0; k0 < CDIM; k0 += 64) {
        // stage A (fp32 -> bf16) and B (bf16), xor-swizzled 16B chunks
        #pragma unroll
        for (int it = 0; it < 4; ++it) {
            int cid = tid + it * 256;       // 1024 chunks of 8 elems
            int r = cid >> 3, c = cid & 7;
            const float* srcA = X + (size_t)(m0 + r) * CDIM + k0 + c * 8;
            float4 f0 = *(const float4*)srcA;
            float4 f1 = *(const float4*)(srcA + 4);
            bf16x8 ha;
            ha[0]=(bf16)f0.x; ha[1]=(bf16)f0.y; ha[2]=(bf16)f0.z; ha[3]=(bf16)f0.w;
            ha[4]=(bf16)f1.x; ha[5]=(bf16)f1.y; ha[6]=(bf16)f1.z; ha[7]=(bf16)f1.w;
            *(bf16x8*)&As[r * 64 + ((c ^ (r & 7))) * 8] = ha;
            *(bf16x8*)&Bs[r * 64 + ((c ^ (r & 7))) * 8] =
                *(const bf16x8*)&Wb[(size_t)(n0 + r) * CDIM + k0 + c * 8];
        }
        __syncthreads();
        #pragma unroll
        for (int ks = 0; ks < 2; ++ks) {
            bf16x8 af[4], bfr[4];
            #pragma unroll
            for (int mi = 0; mi < 4; ++mi) {
                int r = wm + mi * 16 + lr;
                af[mi] = *(const bf16x8*)&As[r * 64 + ((ks * 4 + lq) ^ (r & 7)) * 8];
            }
            #pragma unroll
            for (int ni = 0; ni < 4; ++ni) {
                int r = wn + ni * 16 + lr;
                bfr[ni] = *(const bf16x8*)&Bs[r * 64 + ((ks * 4 + lq) ^ (r & 7)) * 8];
            }
            #pragma unroll
            for (int mi = 0; mi < 4; ++mi)
                #pragma unroll
                for (int ni = 0; ni < 4; ++ni)
                    acc[mi][ni] = __builtin_amdgcn_mfma_f32_16x16x32_bf16(
                        af[mi], bfr[ni], acc[mi][ni], 0, 0, 0);
        }
        __syncthreads();
    }

    // epilogue: section is uniform per block (384 = 3*128)
    const int sec = n0 / CDIM;   // 0=q 1=k 2=v
    #pragma unroll
    for (int mi = 0; mi < 4; ++mi) {
        #pragma unroll
        for (int ni = 0; ni < 4; ++ni) {
            int n = n0 + wn + ni * 16 + lr;
            int c = n - sec * CDIM;
            int hh = c >> 5, d = c & 31;
            #pragma unroll
            for (int r = 0; r < 4; ++r) {
                int m = m0 + wm + mi * 16 + lq * 4 + r;
                int b = m >> 12, i = m & 4095;
                float v = acc[mi][ni][r];
                size_t dst = ((size_t)(b * NHEADS + hh) * SEQ + i) * HD + d;
                if (sec == 0) {
                    qh[dst] = (bf16)fmaxf(v, 0.f);
                } else if (sec == 1) {
                    v += pos[(size_t)i * CDIM + c];
                    kh[dst] = (bf16)fmaxf(v, 0.f);
                } else {
                    vh[dst] = (bf16)v;
                }
            }
        }
    }
}

// ---------------------------------------------------------------- K2: kv + ksum
// grid (KVPARTS, BHN); each block privately reduces 1024 rows; NO atomics.
__global__ __launch_bounds__(256, 2)
void kv_reduce(const bf16* __restrict__ kh, const bf16* __restrict__ vh,
               float* __restrict__ kv_part, float* __restrict__ ksum_part) {
    __shared__ bf16 kl[128 * 32];
    __shared__ bf16 vl[128 * 32];
    __shared__ float red[4 * 1024];
    __shared__ float kred[128];
    const int tid = threadIdx.x;
    const int bh  = blockIdx.y;
    const int part = blockIdx.x;
    const int j0  = part * 1024;
    const int w   = tid >> 6;
    const int c0  = ((tid >> 3) & 7) * 4;
    const int dg  = tid & 7;
    const int d0  = dg * 4;
    const bf16* kbase = kh + (size_t)bh * SEQ * HD;
    const bf16* vbase = vh + (size_t)bh * SEQ * HD;

    float acc[4][4] = {};
    float ksacc[4] = {};

    for (int sc = 0; sc < 8; ++sc) {
        int row0 = j0 + sc * 128;
        #pragma unroll
        for (int it = 0; it < 2; ++it) {
            int cid = tid + it * 256;      // 512 chunks
            int r = cid >> 2, q = cid & 3;
            *(bf16x8*)&kl[r * 32 + q * 8] = *(const bf16x8*)&kbase[(size_t)(row0 + r) * HD + q * 8];
            *(bf16x8*)&vl[r * 32 + q * 8] = *(const bf16x8*)&vbase[(size_t)(row0 + r) * HD + q * 8];
        }
        __syncthreads();
        const int jbeg = w * 32;
        for (int j = jbeg; j < jbeg + 32; ++j) {
            bf16x4 kq = *(const bf16x4*)&kl[j * 32 + c0];
            bf16x4 vq = *(const bf16x4*)&vl[j * 32 + d0];
            float kf[4], vf[4];
            #pragma unroll
            for (int a = 0; a < 4; ++a) { kf[a] = (float)kq[a]; vf[a] = (float)vq[a]; }
            #pragma unroll
            for (int a = 0; a < 4; ++a)
                #pragma unroll
                for (int bb = 0; bb < 4; ++bb) acc[a][bb] += kf[a] * vf[bb];
            if (dg == 0) {
                #pragma unroll
                for (int a = 0; a < 4; ++a) ksacc[a] += kf[a];
            }
        }
        __syncthreads();
    }
    // cross-wave reduce in LDS, then plain stores (no atomics)
    #pragma unroll
    for (int a = 0; a < 4; ++a)
        #pragma unroll
        for (int bb = 0; bb < 4; ++bb)
            red[w * 1024 + (c0 + a) * 32 + d0 + bb] = acc[a][bb];
    if (dg == 0) {
        #pragma unroll
        for (int a = 0; a < 4; ++a) kred[w * 32 + c0 + a] = ksacc[a];
    }
    __syncthreads();
    {
        int e = tid * 4;
        f32x4 s = *(f32x4*)&red[e];
        s += *(f32x4*)&red[1024 + e];
        s += *(f32x4*)&red[2048 + e];
        s += *(f32x4*)&red[3072 + e];
        *(f32x4*)&kv_part[((size_t)bh * KVPARTS + part) * 1024 + e] = s;
    }
    if (tid < 32) {
        ksum_part[((size_t)bh * KVPARTS + part) * 32 + tid] =
            kred[tid] + kred[32 + tid] + kred[64 + tid] + kred[96 + tid];
    }
}

// ---------------------------------------------------------------- K3: out_pre
__global__ __launch_bounds__(256, 2)
void attn_out(const bf16* __restrict__ qh, const bf16* __restrict__ vh,
              const float* __restrict__ kv_part, const float* __restrict__ ksum_part,
              const float* __restrict__ dwcw, const float* __restrict__ dwcb,
              bf16* __restrict__ outp) {
    __shared__ bf16 vt[12 * 64 * 32];   // 48 KB halo tile
    __shared__ float kvl[1024];
    __shared__ float ksl[32];
    __shared__ float wl[25 * 32];
    __shared__ float bl[32];
    const int tid = threadIdx.x;
    const int bh  = blockIdx.y;
    const int ys  = blockIdx.x * 8;     // strip of 8 spatial rows
    const bf16* vbase = vh + (size_t)bh * SEQ * HD;

    #pragma unroll
    for (int it = 0; it < 12; ++it) {
        int cid = tid + it * 256;        // 3072 chunks of 8 bf16
        int vy = cid >> 8;
        int xx = (cid >> 2) & 63;
        int q  = cid & 3;
        int gy = ys + vy - 2;
        bf16x8 val = {};
        if (gy >= 0 && gy < 64)
            val = *(const bf16x8*)&vbase[((size_t)gy * 64 + xx) * HD + q * 8];
        *(bf16x8*)&vt[(vy * 64 + xx) * HD + q * 8] = val;
    }
    {
        const float* kp = kv_part + (size_t)bh * KVPARTS * 1024;
        f32x4 t = *(const f32x4*)&kp[tid * 4];
        t += *(const f32x4*)&kp[1024 + tid * 4];
        t += *(const f32x4*)&kp[2048 + tid * 4];
        t += *(const f32x4*)&kp[3072 + tid * 4];
        *(f32x4*)&kvl[tid * 4] = t;
    }
    if (tid < 32) {
        const float* sp = ksum_part + (size_t)bh * KVPARTS * 32;
        ksl[tid] = sp[tid] + sp[32 + tid] + sp[64 + tid] + sp[96 + tid];
        #pragma unroll
        for (int tap = 0; tap < 25; ++tap) wl[tap * 32 + tid] = dwcw[tid * 25 + tap];
        bl[tid] = dwcb[tid];
    }
    __syncthreads();

    const int dq = tid & 7, d0 = dq * 4;
    const int ri = tid >> 3;            // 0..31
    const int b = bh / NHEADS, hh = bh % NHEADS;
    const bf16* qbase = qh + (size_t)bh * SEQ * HD;

    for (int it = 0; it < 16; ++it) {
        int pix = ri + it * 32;          // 0..511
        int yy = pix >> 6;               // 0..7 within strip
        int x  = pix & 63;
        int tok = (ys + yy) * 64 + x;
        float zden = 1e-6f;
        float dot0 = 0, dot1 = 0, dot2 = 0, dot3 = 0;
        #pragma unroll
        for (int c4 = 0; c4 < 32; c4 += 4) {
            bf16x4 qv = *(const bf16x4*)&qbase[(size_t)tok * HD + c4];
            #pragma unroll
            for (int u = 0; u < 4; ++u) {
                float qf = (float)qv[u];
                int c = c4 + u;
                zden += qf * ksl[c];
                dot0 += qf * kvl[c * 32 + d0];
                dot1 += qf * kvl[c * 32 + d0 + 1];
                dot2 += qf * kvl[c * 32 + d0 + 2];
                dot3 += qf * kvl[c * 32 + d0 + 3];
            }
        }
        float z = 1.f / zden;
        float f0 = bl[d0], f1 = bl[d0 + 1], f2 = bl[d0 + 2], f3 = bl[d0 + 3];
        int vyc = yy + 2;
        #pragma unroll
        for (int dy = -2; dy <= 2; ++dy) {
            #pragma unroll
            for (int dx = -2; dx <= 2; ++dx) {
                int xx = x + dx;
                if (xx < 0 || xx >= 64) continue;
                int tap = (dy + 2) * 5 + (dx + 2);
                bf16x4 vv = *(const bf16x4*)&vt[((vyc + dy) * 64 + xx) * HD + d0];
                const float* wp = &wl[tap * 32 + d0];
                f0 += (float)vv[0] * wp[0];
                f1 += (float)vv[1] * wp[1];
                f2 += (float)vv[2] * wp[2];
                f3 += (float)vv[3] * wp[3];
            }
        }
        bf16x4 ov;
        ov[0] = (bf16)(dot0 * z + f0);
        ov[1] = (bf16)(dot1 * z + f1);
        ov[2] = (bf16)(dot2 * z + f2);
        ov[3] = (bf16)(dot3 * z + f3);
        *(bf16x4*)&outp[((size_t)b * SEQ + tok) * CDIM + hh * HD + d0] = ov;
    }
}

// ---------------------------------------------------------------- K4: proj GEMM
__global__ __launch_bounds__(256, 2)
void gemm_proj(const bf16* __restrict__ A, const bf16* __restrict__ Wb,
               const float* __restrict__ bias, float* __restrict__ out) {
    __shared__ bf16 As[128 * 64];
    __shared__ bf16 Bs[128 * 64];
    const int tid  = threadIdx.x;
    const int lane = tid & 63;
    const int wid  = tid >> 6;
    const int m0   = blockIdx.y * 128;
    const int n0   = blockIdx.x * 128;
    const int wm   = (wid & 1) * 64;
    const int wn   = (wid >> 1) * 64;
    const int lr   = lane & 15;
    const int lq   = lane >> 4;

    f32x4 acc[4][4] = {};

    for (int k0 = 0; k0 < CDIM; k0 += 64) {
        #pragma unroll
        for (int it = 0; it < 4; ++it) {
            int cid = tid + it * 256;
            int r = cid >> 3, c = cid & 7;
            *(bf16x8*)&As[r * 64 + ((c ^ (r & 7))) * 8] =
                *(const bf16x8*)&A[(size_t)(m0 + r) * CDIM + k0 + c * 8];
            *(bf16x8*)&Bs[r * 64 + ((c ^ (r & 7))) * 8] =
                *(const bf16x8*)&Wb[(size_t)(n0 + r) * CDIM + k0 + c * 8];
        }
        __syncthreads();
        #pragma unroll
        for (int ks = 0; ks < 2; ++ks) {
            bf16x8 af[4], bfr[4];
            #pragma unroll
            for (int mi = 0; mi < 4; ++mi) {
                int r = wm + mi * 16 + lr;
                af[mi] = *(const bf16x8*)&As[r * 64 + ((ks * 4 + lq) ^ (r & 7)) * 8];
            }
            #pragma unroll
            for (int ni = 0; ni < 4; ++ni) {
                int r = wn + ni * 16 + lr;
                bfr[ni] = *(const bf16x8*)&Bs[r * 64 + ((ks * 4 + lq) ^ (r & 7)) * 8];
            }
            #pragma unroll
            for (int mi = 0; mi < 4; ++mi)
                #pragma unroll
                for (int ni = 0; ni < 4; ++ni)
                    acc[mi][ni] = __builtin_amdgcn_mfma_f32_16x16x32_bf16(
                        af[mi], bfr[ni], acc[mi][ni], 0, 0, 0);
        }
        __syncthreads();
    }

    #pragma unroll
    for (int mi = 0; mi < 4; ++mi) {
        #pragma unroll
        for (int ni = 0; ni < 4; ++ni) {
            int n = n0 + wn + ni * 16 + lr;
            float bv = bias[n];
            #pragma unroll
            for (int r = 0; r < 4; ++r) {
                int m = m0 + wm + mi * 16 + lq * 4 + r;
                out[(size_t)m * CDIM + n] = acc[mi][ni][r] + bv;
            }
        }
    }
}

// ---------------------------------------------------------------- launch
extern "C" void kernel_launch(void* const* d_in, const int* in_sizes, int n_in,
                              void* d_out, int out_size, void* d_ws, size_t ws_size,
                              hipStream_t stream) {
    const float* x     = (const float*)d_in[0];
    const float* qkvw  = (const float*)d_in[1];
    const float* pos   = (const float*)d_in[2];
    const float* dwcw  = (const float*)d_in[3];
    const float* dwcb  = (const float*)d_in[4];
    const float* projw = (const float*)d_in[5];
    const float* projb = (const float*)d_in[6];
    float* out = (float*)d_out;

    char* ws = (char*)d_ws;
    size_t off = 0;
    auto alloc = [&](size_t bytes) -> void* {
        void* p = ws + off;
        off += (bytes + 255) & ~(size_t)255;
        return p;
    };
    bf16* qkvw_b = (bf16*)alloc((size_t)3 * CDIM * CDIM * 2);
    bf16* projw_b = (bf16*)alloc((size_t)CDIM * CDIM * 2);
    bf16* qh  = (bf16*)alloc((size_t)BHN * SEQ * HD * 2);
    bf16* khb = (bf16*)alloc((size_t)BHN * SEQ * HD * 2);   // reused as out_pre
    bf16* vh  = (bf16*)alloc((size_t)BHN * SEQ * HD * 2);
    float* kvb   = (float*)alloc((size_t)BHN * KVPARTS * HD * HD * 4);
    float* ksumb = (float*)alloc((size_t)BHN * KVPARTS * HD * 4);

    hipLaunchKernelGGL(convert_w, dim3(512), dim3(256), 0, stream,
                       qkvw, projw, qkvw_b, projw_b);
    hipLaunchKernelGGL(gemm_qkv, dim3(9, 512), dim3(256), 0, stream,
                       x, qkvw_b, pos, qh, khb, vh);
    hipLaunchKernelGGL(kv_reduce, dim3(KVPARTS, BHN), dim3(256), 0, stream,
                       khb, vh, kvb, ksumb);
    bf16* outp = khb;   // kh is dead after kv_reduce; reuse as out_pre
    hipLaunchKernelGGL(attn_out, dim3(8, BHN), dim3(256), 0, stream,
                       qh, vh, kvb, ksumb, dwcw, dwcb, outp);
    hipLaunchKernelGGL(gemm_proj, dim3(3, 512), dim3(256), 0, stream,
                       outp, projw_b, projb, out);
}

// Round 3
// 526.398 us; speedup vs baseline: 8.1141x; 8.1141x over previous
//
#include <hip/hip_runtime.h>
#include <hip/hip_bf16.h>
#include <cstdint>
#include <cstddef>

// SlabAttention on MI355X (gfx950).
// Stage 1: qkv = x @ qkv_w^T  (bf16 MFMA 16x16x32, 128x128 tiles)
//          epilogue: q=relu(q); k=relu(k+pos); scatter to (BH,N,32) bf16
// Stage 2: kv_part[bh,2] = k^T v via MFMA 32x32x16 (2 partials, no atomics,
//          no per-thread arrays -> nothing can spill to scratch)
// Stage 3: out_pre = (q@kv)*z + dwconv5x5(v) + b,  z = 1/(q.ksum+eps) -> (B,N,C) bf16
// Stage 4: out = out_pre @ proj_w^T + proj_b  (bf16 MFMA, fp32 out)

typedef __bf16 bf16;
typedef __attribute__((ext_vector_type(8))) __bf16 bf16x8;
typedef __attribute__((ext_vector_type(4))) __bf16 bf16x4;
typedef __attribute__((ext_vector_type(4))) float f32x4;
typedef __attribute__((ext_vector_type(16))) float f32x16;

#define NHEADS 12
#define HD 32
#define BATCH 16
#define SEQ 4096
#define CDIM 384
#define BHN (BATCH*NHEADS)   // 192
#define KVPARTS 2

// ---------------------------------------------------------------- K0: convert
__global__ void convert_w(const float* __restrict__ qkvw, const float* __restrict__ projw,
                          bf16* __restrict__ qkvw_b, bf16* __restrict__ projw_b) {
    int i = blockIdx.x * 256 + threadIdx.x;
    int stride = gridDim.x * 256;
    const int nq = 3 * CDIM * CDIM;      // 442368
    const int np = CDIM * CDIM;          // 147456
    for (int idx = i; idx < nq; idx += stride) qkvw_b[idx] = (bf16)qkvw[idx];
    for (int idx = i; idx < np; idx += stride) projw_b[idx] = (bf16)projw[idx];
}

// ---------------------------------------------------------------- K1: qkv GEMM
// A = x fp32 (65536 x 384), B = qkv_w bf16 (1152 x 384) both K-contiguous.
__global__ __launch_bounds__(256, 2)
void gemm_qkv(const float* __restrict__ X, const bf16* __restrict__ Wb,
              const float* __restrict__ pos,
              bf16* __restrict__ qh, bf16* __restrict__ kh, bf16* __restrict__ vh) {
    __shared__ bf16 As[128 * 64];
    __shared__ bf16 Bs[128 * 64];
    const int tid  = threadIdx.x;
    const int lane = tid & 63;
    const int wid  = tid >> 6;
    const int m0   = blockIdx.y * 128;
    const int n0   = blockIdx.x * 128;
    const int wm   = (wid & 1) * 64;
    const int wn   = (wid >> 1) * 64;
    const int lr   = lane & 15;   // fragment row/col
    const int lq   = lane >> 4;   // quad

    f32x4 acc[4][4] = {};

    for (int k0 = 0; k0 < CDIM; k0 += 64) {
        // stage A (fp32 -> bf16) and B (bf16), xor-swizzled 16B chunks
        #pragma unroll
        for (int it = 0; it < 4; ++it) {
            int cid = tid + it * 256;       // 1024 chunks of 8 elems
            int r = cid >> 3, c = cid & 7;
            const float* srcA = X + (size_t)(m0 + r) * CDIM + k0 + c * 8;
            float4 f0 = *(const float4*)srcA;
            float4 f1 = *(const float4*)(srcA + 4);
            bf16x8 ha;
            ha[0]=(bf16)f0.x; ha[1]=(bf16)f0.y; ha[2]=(bf16)f0.z; ha[3]=(bf16)f0.w;
            ha[4]=(bf16)f1.x; ha[5]=(bf16)f1.y; ha[6]=(bf16)f1.z; ha[7]=(bf16)f1.w;
            *(bf16x8*)&As[r * 64 + ((c ^ (r & 7))) * 8] = ha;
            *(bf16x8*)&Bs[r * 64 + ((c ^ (r & 7))) * 8] =
                *(const bf16x8*)&Wb[(size_t)(n0 + r) * CDIM + k0 + c * 8];
        }
        __syncthreads();
        #pragma unroll
        for (int ks = 0; ks < 2; ++ks) {
            bf16x8 af[4], bfr[4];
            #pragma unroll
            for (int mi = 0; mi < 4; ++mi) {
                int r = wm + mi * 16 + lr;
                af[mi] = *(const bf16x8*)&As[r * 64 + ((ks * 4 + lq) ^ (r & 7)) * 8];
            }
            #pragma unroll
            for (int ni = 0; ni < 4; ++ni) {
                int r = wn + ni * 16 + lr;
                bfr[ni] = *(const bf16x8*)&Bs[r * 64 + ((ks * 4 + lq) ^ (r & 7)) * 8];
            }
            #pragma unroll
            for (int mi = 0; mi < 4; ++mi)
                #pragma unroll
                for (int ni = 0; ni < 4; ++ni)
                    acc[mi][ni] = __builtin_amdgcn_mfma_f32_16x16x32_bf16(
                        af[mi], bfr[ni], acc[mi][ni], 0, 0, 0);
        }
        __syncthreads();
    }

    // epilogue: section is uniform per block (384 = 3*128)
    const int sec = n0 / CDIM;   // 0=q 1=k 2=v
    #pragma unroll
    for (int mi = 0; mi < 4; ++mi) {
        #pragma unroll
        for (int ni = 0; ni < 4; ++ni) {
            int n = n0 + wn + ni * 16 + lr;
            int c = n - sec * CDIM;
            int hh = c >> 5, d = c & 31;
            #pragma unroll
            for (int r = 0; r < 4; ++r) {
                int m = m0 + wm + mi * 16 + lq * 4 + r;
                int b = m >> 12, i = m & 4095;
                float v = acc[mi][ni][r];
                size_t dst = ((size_t)(b * NHEADS + hh) * SEQ + i) * HD + d;
                if (sec == 0) {
                    qh[dst] = (bf16)fmaxf(v, 0.f);
                } else if (sec == 1) {
                    v += pos[(size_t)i * CDIM + c];
                    kh[dst] = (bf16)fmaxf(v, 0.f);
                } else {
                    vh[dst] = (bf16)v;
                }
            }
        }
    }
}

// ---------------------------------------------------------------- K2: kv + ksum (MFMA)
// grid (KVPARTS, BHN), 4 waves/block, 512 rows/wave.
// kv[c][d] = sum_j k[j][c] v[j][d]  == (k^T) @ v : M=N=32, K=4096.
// A-fragment of k^T gathered from k's natural layout == B-pattern gather.
// ksum via second MFMA with B = ones (fp32-exact).
__global__ __launch_bounds__(256, 2)
void kv_mfma(const bf16* __restrict__ kh, const bf16* __restrict__ vh,
             float* __restrict__ kv_part, float* __restrict__ ksum_part) {
    __shared__ float red[4 * 1024];
    __shared__ float ksred[4 * 32];
    const int tid  = threadIdx.x;
    const int lane = tid & 63;
    const int w    = tid >> 6;
    const int bh   = blockIdx.y;
    const int part = blockIdx.x;
    const int col  = lane & 31;
    const int half = lane >> 5;
    const bf16* kb = kh + (size_t)bh * SEQ * HD;
    const bf16* vb = vh + (size_t)bh * SEQ * HD;
    const int j0 = part * 2048 + w * 512;

    f32x16 acc = {};
    f32x16 aks = {};
    bf16x8 ones;
    #pragma unroll
    for (int j = 0; j < 8; ++j) ones[j] = (bf16)1.0f;

    for (int s = 0; s < 32; ++s) {
        int jb = j0 + s * 16 + half * 8;
        bf16x8 afr, bfr;
        #pragma unroll
        for (int j = 0; j < 8; ++j) {
            afr[j] = kb[(size_t)(jb + j) * HD + col];
            bfr[j] = vb[(size_t)(jb + j) * HD + col];
        }
        acc = __builtin_amdgcn_mfma_f32_32x32x16_bf16(afr, bfr, acc, 0, 0, 0);
        aks = __builtin_amdgcn_mfma_f32_32x32x16_bf16(afr, ones, aks, 0, 0, 0);
    }

    // C/D layout: col = lane&31, row = (r&3) + 8*(r>>2) + 4*half
    #pragma unroll
    for (int r = 0; r < 16; ++r) {
        int row = (r & 3) + 8 * (r >> 2) + 4 * half;
        red[w * 1024 + row * 32 + col] = acc[r];
        ksred[w * 32 + row] = aks[r];    // same-value benign race across col
    }
    __syncthreads();
    {
        int e = tid * 4;
        f32x4 s4 = *(f32x4*)&red[e];
        s4 += *(f32x4*)&red[1024 + e];
        s4 += *(f32x4*)&red[2048 + e];
        s4 += *(f32x4*)&red[3072 + e];
        *(f32x4*)&kv_part[((size_t)bh * KVPARTS + part) * 1024 + e] = s4;
    }
    if (tid < 32) {
        ksum_part[((size_t)bh * KVPARTS + part) * 32 + tid] =
            ksred[tid] + ksred[32 + tid] + ksred[64 + tid] + ksred[96 + tid];
    }
}

// ---------------------------------------------------------------- K3: out_pre
__global__ __launch_bounds__(256, 2)
void attn_out(const bf16* __restrict__ qh, const bf16* __restrict__ vh,
              const float* __restrict__ kv_part, const float* __restrict__ ksum_part,
              const float* __restrict__ dwcw, const float* __restrict__ dwcb,
              bf16* __restrict__ outp) {
    __shared__ bf16 vt[12 * 64 * 32];   // 48 KB halo tile
    __shared__ float kvl[1024];
    __shared__ float ksl[32];
    __shared__ float wl[25 * 32];
    __shared__ float bl[32];
    const int tid = threadIdx.x;
    const int bh  = blockIdx.y;
    const int ys  = blockIdx.x * 8;     // strip of 8 spatial rows
    const bf16* vbase = vh + (size_t)bh * SEQ * HD;

    #pragma unroll
    for (int it = 0; it < 12; ++it) {
        int cid = tid + it * 256;        // 3072 chunks of 8 bf16
        int vy = cid >> 8;
        int xx = (cid >> 2) & 63;
        int q  = cid & 3;
        int gy = ys + vy - 2;
        bf16x8 val = {};
        if (gy >= 0 && gy < 64)
            val = *(const bf16x8*)&vbase[((size_t)gy * 64 + xx) * HD + q * 8];
        *(bf16x8*)&vt[(vy * 64 + xx) * HD + q * 8] = val;
    }
    {
        const float* kp = kv_part + (size_t)bh * KVPARTS * 1024;
        f32x4 t = *(const f32x4*)&kp[tid * 4];
        t += *(const f32x4*)&kp[1024 + tid * 4];
        *(f32x4*)&kvl[tid * 4] = t;
    }
    if (tid < 32) {
        const float* sp = ksum_part + (size_t)bh * KVPARTS * 32;
        ksl[tid] = sp[tid] + sp[32 + tid];
        #pragma unroll
        for (int tap = 0; tap < 25; ++tap) wl[tap * 32 + tid] = dwcw[tid * 25 + tap];
        bl[tid] = dwcb[tid];
    }
    __syncthreads();

    const int dq = tid & 7, d0 = dq * 4;
    const int ri = tid >> 3;            // 0..31
    const int b = bh / NHEADS, hh = bh % NHEADS;
    const bf16* qbase = qh + (size_t)bh * SEQ * HD;

    for (int it = 0; it < 16; ++it) {
        int pix = ri + it * 32;          // 0..511
        int yy = pix >> 6;               // 0..7 within strip
        int x  = pix & 63;
        int tok = (ys + yy) * 64 + x;
        float zden = 1e-6f;
        float dot0 = 0, dot1 = 0, dot2 = 0, dot3 = 0;
        #pragma unroll
        for (int c4 = 0; c4 < 32; c4 += 4) {
            bf16x4 qv = *(const bf16x4*)&qbase[(size_t)tok * HD + c4];
            #pragma unroll
            for (int u = 0; u < 4; ++u) {
                float qf = (float)qv[u];
                int c = c4 + u;
                zden += qf * ksl[c];
                dot0 += qf * kvl[c * 32 + d0];
                dot1 += qf * kvl[c * 32 + d0 + 1];
                dot2 += qf * kvl[c * 32 + d0 + 2];
                dot3 += qf * kvl[c * 32 + d0 + 3];
            }
        }
        float z = 1.f / zden;
        float f0 = bl[d0], f1 = bl[d0 + 1], f2 = bl[d0 + 2], f3 = bl[d0 + 3];
        int vyc = yy + 2;
        #pragma unroll
        for (int dy = -2; dy <= 2; ++dy) {
            #pragma unroll
            for (int dx = -2; dx <= 2; ++dx) {
                int xx = x + dx;
                if (xx < 0 || xx >= 64) continue;
                int tap = (dy + 2) * 5 + (dx + 2);
                bf16x4 vv = *(const bf16x4*)&vt[((vyc + dy) * 64 + xx) * HD + d0];
                const float* wp = &wl[tap * 32 + d0];
                f0 += (float)vv[0] * wp[0];
                f1 += (float)vv[1] * wp[1];
                f2 += (float)vv[2] * wp[2];
                f3 += (float)vv[3] * wp[3];
            }
        }
        bf16x4 ov;
        ov[0] = (bf16)(dot0 * z + f0);
        ov[1] = (bf16)(dot1 * z + f1);
        ov[2] = (bf16)(dot2 * z + f2);
        ov[3] = (bf16)(dot3 * z + f3);
        *(bf16x4*)&outp[((size_t)b * SEQ + tok) * CDIM + hh * HD + d0] = ov;
    }
}

// ---------------------------------------------------------------- K4: proj GEMM
__global__ __launch_bounds__(256, 2)
void gemm_proj(const bf16* __restrict__ A, const bf16* __restrict__ Wb,
               const float* __restrict__ bias, float* __restrict__ out) {
    __shared__ bf16 As[128 * 64];
    __shared__ bf16 Bs[128 * 64];
    const int tid  = threadIdx.x;
    const int lane = tid & 63;
    const int wid  = tid >> 6;
    const int m0   = blockIdx.y * 128;
    const int n0   = blockIdx.x * 128;
    const int wm   = (wid & 1) * 64;
    const int wn   = (wid >> 1) * 64;
    const int lr   = lane & 15;
    const int lq   = lane >> 4;

    f32x4 acc[4][4] = {};

    for (int k0 = 0; k0 < CDIM; k0 += 64) {
        #pragma unroll
        for (int it = 0; it < 4; ++it) {
            int cid = tid + it * 256;
            int r = cid >> 3, c = cid & 7;
            *(bf16x8*)&As[r * 64 + ((c ^ (r & 7))) * 8] =
                *(const bf16x8*)&A[(size_t)(m0 + r) * CDIM + k0 + c * 8];
            *(bf16x8*)&Bs[r * 64 + ((c ^ (r & 7))) * 8] =
                *(const bf16x8*)&Wb[(size_t)(n0 + r) * CDIM + k0 + c * 8];
        }
        __syncthreads();
        #pragma unroll
        for (int ks = 0; ks < 2; ++ks) {
            bf16x8 af[4], bfr[4];
            #pragma unroll
            for (int mi = 0; mi < 4; ++mi) {
                int r = wm + mi * 16 + lr;
                af[mi] = *(const bf16x8*)&As[r * 64 + ((ks * 4 + lq) ^ (r & 7)) * 8];
            }
            #pragma unroll
            for (int ni = 0; ni < 4; ++ni) {
                int r = wn + ni * 16 + lr;
                bfr[ni] = *(const bf16x8*)&Bs[r * 64 + ((ks * 4 + lq) ^ (r & 7)) * 8];
            }
            #pragma unroll
            for (int mi = 0; mi < 4; ++mi)
                #pragma unroll
                for (int ni = 0; ni < 4; ++ni)
                    acc[mi][ni] = __builtin_amdgcn_mfma_f32_16x16x32_bf16(
                        af[mi], bfr[ni], acc[mi][ni], 0, 0, 0);
        }
        __syncthreads();
    }

    #pragma unroll
    for (int mi = 0; mi < 4; ++mi) {
        #pragma unroll
        for (int ni = 0; ni < 4; ++ni) {
            int n = n0 + wn + ni * 16 + lr;
            float bv = bias[n];
            #pragma unroll
            for (int r = 0; r < 4; ++r) {
                int m = m0 + wm + mi * 16 + lq * 4 + r;
                out[(size_t)m * CDIM + n] = acc[mi][ni][r] + bv;
            }
        }
    }
}

// ---------------------------------------------------------------- launch
extern "C" void kernel_launch(void* const* d_in, const int* in_sizes, int n_in,
                              void* d_out, int out_size, void* d_ws, size_t ws_size,
                              hipStream_t stream) {
    const float* x     = (const float*)d_in[0];
    const float* qkvw  = (const float*)d_in[1];
    const float* pos   = (const float*)d_in[2];
    const float* dwcw  = (const float*)d_in[3];
    const float* dwcb  = (const float*)d_in[4];
    const float* projw = (const float*)d_in[5];
    const float* projb = (const float*)d_in[6];
    float* out = (float*)d_out;

    char* ws = (char*)d_ws;
    size_t off = 0;
    auto alloc = [&](size_t bytes) -> void* {
        void* p = ws + off;
        off += (bytes + 255) & ~(size_t)255;
        return p;
    };
    bf16* qkvw_b = (bf16*)alloc((size_t)3 * CDIM * CDIM * 2);
    bf16* projw_b = (bf16*)alloc((size_t)CDIM * CDIM * 2);
    bf16* qh  = (bf16*)alloc((size_t)BHN * SEQ * HD * 2);
    bf16* khb = (bf16*)alloc((size_t)BHN * SEQ * HD * 2);   // reused as out_pre
    bf16* vh  = (bf16*)alloc((size_t)BHN * SEQ * HD * 2);
    float* kvb   = (float*)alloc((size_t)BHN * KVPARTS * HD * HD * 4);
    float* ksumb = (float*)alloc((size_t)BHN * KVPARTS * HD * 4);

    hipLaunchKernelGGL(convert_w, dim3(512), dim3(256), 0, stream,
                       qkvw, projw, qkvw_b, projw_b);
    hipLaunchKernelGGL(gemm_qkv, dim3(9, 512), dim3(256), 0, stream,
                       x, qkvw_b, pos, qh, khb, vh);
    hipLaunchKernelGGL(kv_mfma, dim3(KVPARTS, BHN), dim3(256), 0, stream,
                       khb, vh, kvb, ksumb);
    bf16* outp = khb;   // kh is dead after kv_mfma; reuse as out_pre
    hipLaunchKernelGGL(attn_out, dim3(8, BHN), dim3(256), 0, stream,
                       qh, vh, kvb, ksumb, dwcw, dwcb, outp);
    hipLaunchKernelGGL(gemm_proj, dim3(3, 512), dim3(256), 0, stream,
                       outp, projw_b, projb, out);
}

// Round 4
// 475.597 us; speedup vs baseline: 8.9809x; 1.1068x over previous
//
#include <hip/hip_runtime.h>
#include <hip/hip_bf16.h>
#include <cstdint>
#include <cstddef>

// SlabAttention on MI355X (gfx950).
// Stage 0: convert x, qkv_w, proj_w to bf16
// Stage 1: qkv = x @ qkv_w^T  (bf16 MFMA, 128x128 tiles, global_load_lds
//          staging, XCD-swizzled grid so each XCD reuses its A-tiles via L2)
// Stage 2: kv_part[bh,2] = k^T v via MFMA 32x32x16 (no atomics)
// Stage 3: out_pre = (q@kv)*z + dwconv5x5(v) + b -> (B,N,C) bf16
// Stage 4: out = out_pre @ proj_w^T + proj_b  (bf16 MFMA, fp32 out)

typedef __bf16 bf16;
typedef __attribute__((ext_vector_type(8))) __bf16 bf16x8;
typedef __attribute__((ext_vector_type(4))) __bf16 bf16x4;
typedef __attribute__((ext_vector_type(4))) float f32x4;
typedef __attribute__((ext_vector_type(16))) float f32x16;

#define NHEADS 12
#define HD 32
#define BATCH 16
#define SEQ 4096
#define CDIM 384
#define BHN (BATCH*NHEADS)   // 192
#define KVPARTS 2

// async global->LDS, 16 B per lane; dest must be lane-linear from wave base
__device__ __forceinline__ void gl_lds16(const bf16* g, bf16* l) {
    __builtin_amdgcn_global_load_lds(
        (const __attribute__((address_space(1))) unsigned int*)g,
        (__attribute__((address_space(3))) unsigned int*)l, 16, 0, 0);
}

// ---------------------------------------------------------------- K0: convert
__global__ void convert_in(const float* __restrict__ X, const float* __restrict__ qkvw,
                           const float* __restrict__ projw,
                           bf16* __restrict__ xb, bf16* __restrict__ qkvw_b,
                           bf16* __restrict__ projw_b) {
    int i = blockIdx.x * 256 + threadIdx.x;
    int stride = gridDim.x * 256;
    const int nx = (65536 * CDIM) / 8;      // 3145728 chunks of 8
    for (int c = i; c < nx; c += stride) {
        const float* s = X + (size_t)c * 8;
        float4 f0 = *(const float4*)s;
        float4 f1 = *(const float4*)(s + 4);
        bf16x8 h;
        h[0]=(bf16)f0.x; h[1]=(bf16)f0.y; h[2]=(bf16)f0.z; h[3]=(bf16)f0.w;
        h[4]=(bf16)f1.x; h[5]=(bf16)f1.y; h[6]=(bf16)f1.z; h[7]=(bf16)f1.w;
        *(bf16x8*)&xb[(size_t)c * 8] = h;
    }
    const int nq = (3 * CDIM * CDIM) / 8;
    for (int c = i; c < nq; c += stride) {
        const float* s = qkvw + (size_t)c * 8;
        float4 f0 = *(const float4*)s;
        float4 f1 = *(const float4*)(s + 4);
        bf16x8 h;
        h[0]=(bf16)f0.x; h[1]=(bf16)f0.y; h[2]=(bf16)f0.z; h[3]=(bf16)f0.w;
        h[4]=(bf16)f1.x; h[5]=(bf16)f1.y; h[6]=(bf16)f1.z; h[7]=(bf16)f1.w;
        *(bf16x8*)&qkvw_b[(size_t)c * 8] = h;
    }
    const int np = (CDIM * CDIM) / 8;
    for (int c = i; c < np; c += stride) {
        const float* s = projw + (size_t)c * 8;
        float4 f0 = *(const float4*)s;
        float4 f1 = *(const float4*)(s + 4);
        bf16x8 h;
        h[0]=(bf16)f0.x; h[1]=(bf16)f0.y; h[2]=(bf16)f0.z; h[3]=(bf16)f0.w;
        h[4]=(bf16)f1.x; h[5]=(bf16)f1.y; h[6]=(bf16)f1.z; h[7]=(bf16)f1.w;
        *(bf16x8*)&projw_b[(size_t)c * 8] = h;
    }
}

// ---------------------------------------------------------------- K1: qkv GEMM
// A = xb bf16 (65536 x 384), B = qkv_w bf16 (1152 x 384), K-contiguous.
// 1D grid of 4608 blocks; xcd-swizzled: work = (b%8)*576 + b/8, mt=work/9, nt=work%9.
__global__ __launch_bounds__(256, 2)
void gemm_qkv(const bf16* __restrict__ X, const bf16* __restrict__ Wb,
              const float* __restrict__ pos,
              bf16* __restrict__ qh, bf16* __restrict__ kh, bf16* __restrict__ vh) {
    __shared__ bf16 As[128 * 64];
    __shared__ bf16 Bs[128 * 64];
    const int tid  = threadIdx.x;
    const int lane = tid & 63;
    const int wid  = tid >> 6;
    const int blk  = blockIdx.x;
    const int work = (blk & 7) * (4608 / 8) + (blk >> 3);
    const int mt   = work / 9;
    const int nt   = work - mt * 9;
    const int m0   = mt * 128;
    const int n0   = nt * 128;
    const int wm   = (wid & 1) * 64;
    const int wn   = (wid >> 1) * 64;
    const int lr   = lane & 15;   // fragment row/col
    const int lq   = lane >> 4;   // quad

    // staging geometry: wave w, iter it covers rows [w*32+it*8, +8), lane l:
    // row r = base + (l>>3), source chunk = (l&7) ^ (r&7), dest lane-linear.
    const int srow = (lane >> 3);
    const int sc   = lane & 7;

    f32x4 acc[4][4] = {};

    for (int k0 = 0; k0 < CDIM; k0 += 64) {
        #pragma unroll
        for (int it = 0; it < 4; ++it) {
            int rbase = wid * 32 + it * 8;
            int r = rbase + srow;
            int gc = sc ^ (r & 7);
            gl_lds16(&X [(size_t)(m0 + r) * CDIM + k0 + gc * 8], &As[rbase * 64]);
            gl_lds16(&Wb[(size_t)(n0 + r) * CDIM + k0 + gc * 8], &Bs[rbase * 64]);
        }
        __syncthreads();
        #pragma unroll
        for (int ks = 0; ks < 2; ++ks) {
            bf16x8 af[4], bfr[4];
            #pragma unroll
            for (int mi = 0; mi < 4; ++mi) {
                int r = wm + mi * 16 + lr;
                af[mi] = *(const bf16x8*)&As[r * 64 + ((ks * 4 + lq) ^ (r & 7)) * 8];
            }
            #pragma unroll
            for (int ni = 0; ni < 4; ++ni) {
                int r = wn + ni * 16 + lr;
                bfr[ni] = *(const bf16x8*)&Bs[r * 64 + ((ks * 4 + lq) ^ (r & 7)) * 8];
            }
            #pragma unroll
            for (int mi = 0; mi < 4; ++mi)
                #pragma unroll
                for (int ni = 0; ni < 4; ++ni)
                    acc[mi][ni] = __builtin_amdgcn_mfma_f32_16x16x32_bf16(
                        af[mi], bfr[ni], acc[mi][ni], 0, 0, 0);
        }
        __syncthreads();
    }

    // epilogue: section is uniform per block (384 = 3*128)
    const int sec = n0 / CDIM;   // 0=q 1=k 2=v
    #pragma unroll
    for (int mi = 0; mi < 4; ++mi) {
        #pragma unroll
        for (int ni = 0; ni < 4; ++ni) {
            int n = n0 + wn + ni * 16 + lr;
            int c = n - sec * CDIM;
            int hh = c >> 5, d = c & 31;
            #pragma unroll
            for (int r = 0; r < 4; ++r) {
                int m = m0 + wm + mi * 16 + lq * 4 + r;
                int b = m >> 12, i = m & 4095;
                float v = acc[mi][ni][r];
                size_t dst = ((size_t)(b * NHEADS + hh) * SEQ + i) * HD + d;
                if (sec == 0) {
                    qh[dst] = (bf16)fmaxf(v, 0.f);
                } else if (sec == 1) {
                    v += pos[(size_t)i * CDIM + c];
                    kh[dst] = (bf16)fmaxf(v, 0.f);
                } else {
                    vh[dst] = (bf16)v;
                }
            }
        }
    }
}

// ---------------------------------------------------------------- K2: kv + ksum (MFMA)
__global__ __launch_bounds__(256, 2)
void kv_mfma(const bf16* __restrict__ kh, const bf16* __restrict__ vh,
             float* __restrict__ kv_part, float* __restrict__ ksum_part) {
    __shared__ float red[4 * 1024];
    __shared__ float ksred[4 * 32];
    const int tid  = threadIdx.x;
    const int lane = tid & 63;
    const int w    = tid >> 6;
    const int bh   = blockIdx.y;
    const int part = blockIdx.x;
    const int col  = lane & 31;
    const int half = lane >> 5;
    const bf16* kb = kh + (size_t)bh * SEQ * HD;
    const bf16* vb = vh + (size_t)bh * SEQ * HD;
    const int j0 = part * 2048 + w * 512;

    f32x16 acc = {};
    f32x16 aks = {};
    bf16x8 ones;
    #pragma unroll
    for (int j = 0; j < 8; ++j) ones[j] = (bf16)1.0f;

    for (int s = 0; s < 32; ++s) {
        int jb = j0 + s * 16 + half * 8;
        bf16x8 afr, bfr;
        #pragma unroll
        for (int j = 0; j < 8; ++j) {
            afr[j] = kb[(size_t)(jb + j) * HD + col];
            bfr[j] = vb[(size_t)(jb + j) * HD + col];
        }
        acc = __builtin_amdgcn_mfma_f32_32x32x16_bf16(afr, bfr, acc, 0, 0, 0);
        aks = __builtin_amdgcn_mfma_f32_32x32x16_bf16(afr, ones, aks, 0, 0, 0);
    }

    #pragma unroll
    for (int r = 0; r < 16; ++r) {
        int row = (r & 3) + 8 * (r >> 2) + 4 * half;
        red[w * 1024 + row * 32 + col] = acc[r];
        ksred[w * 32 + row] = aks[r];
    }
    __syncthreads();
    {
        int e = tid * 4;
        f32x4 s4 = *(f32x4*)&red[e];
        s4 += *(f32x4*)&red[1024 + e];
        s4 += *(f32x4*)&red[2048 + e];
        s4 += *(f32x4*)&red[3072 + e];
        *(f32x4*)&kv_part[((size_t)bh * KVPARTS + part) * 1024 + e] = s4;
    }
    if (tid < 32) {
        ksum_part[((size_t)bh * KVPARTS + part) * 32 + tid] =
            ksred[tid] + ksred[32 + tid] + ksred[64 + tid] + ksred[96 + tid];
    }
}

// ---------------------------------------------------------------- K3: out_pre
__global__ __launch_bounds__(256, 2)
void attn_out(const bf16* __restrict__ qh, const bf16* __restrict__ vh,
              const float* __restrict__ kv_part, const float* __restrict__ ksum_part,
              const float* __restrict__ dwcw, const float* __restrict__ dwcb,
              bf16* __restrict__ outp) {
    __shared__ bf16 vt[12 * 64 * 32];   // 48 KB halo tile
    __shared__ float kvl[1024];
    __shared__ float ksl[32];
    __shared__ float wl[25 * 32];
    __shared__ float bl[32];
    const int tid = threadIdx.x;
    const int bh  = blockIdx.y;
    const int ys  = blockIdx.x * 8;     // strip of 8 spatial rows
    const bf16* vbase = vh + (size_t)bh * SEQ * HD;

    #pragma unroll
    for (int it = 0; it < 12; ++it) {
        int cid = tid + it * 256;        // 3072 chunks of 8 bf16
        int vy = cid >> 8;
        int xx = (cid >> 2) & 63;
        int q  = cid & 3;
        int gy = ys + vy - 2;
        bf16x8 val = {};
        if (gy >= 0 && gy < 64)
            val = *(const bf16x8*)&vbase[((size_t)gy * 64 + xx) * HD + q * 8];
        *(bf16x8*)&vt[(vy * 64 + xx) * HD + q * 8] = val;
    }
    {
        const float* kp = kv_part + (size_t)bh * KVPARTS * 1024;
        f32x4 t = *(const f32x4*)&kp[tid * 4];
        t += *(const f32x4*)&kp[1024 + tid * 4];
        *(f32x4*)&kvl[tid * 4] = t;
    }
    if (tid < 32) {
        const float* sp = ksum_part + (size_t)bh * KVPARTS * 32;
        ksl[tid] = sp[tid] + sp[32 + tid];
        #pragma unroll
        for (int tap = 0; tap < 25; ++tap) wl[tap * 32 + tid] = dwcw[tid * 25 + tap];
        bl[tid] = dwcb[tid];
    }
    __syncthreads();

    const int dq = tid & 7, d0 = dq * 4;
    const int ri = tid >> 3;            // 0..31
    const int b = bh / NHEADS, hh = bh % NHEADS;
    const bf16* qbase = qh + (size_t)bh * SEQ * HD;

    for (int it = 0; it < 16; ++it) {
        int pix = ri + it * 32;          // 0..511
        int yy = pix >> 6;               // 0..7 within strip
        int x  = pix & 63;
        int tok = (ys + yy) * 64 + x;
        float zden = 1e-6f;
        float dot0 = 0, dot1 = 0, dot2 = 0, dot3 = 0;
        #pragma unroll
        for (int c4 = 0; c4 < 32; c4 += 4) {
            bf16x4 qv = *(const bf16x4*)&qbase[(size_t)tok * HD + c4];
            #pragma unroll
            for (int u = 0; u < 4; ++u) {
                float qf = (float)qv[u];
                int c = c4 + u;
                zden += qf * ksl[c];
                dot0 += qf * kvl[c * 32 + d0];
                dot1 += qf * kvl[c * 32 + d0 + 1];
                dot2 += qf * kvl[c * 32 + d0 + 2];
                dot3 += qf * kvl[c * 32 + d0 + 3];
            }
        }
        float z = 1.f / zden;
        float f0 = bl[d0], f1 = bl[d0 + 1], f2 = bl[d0 + 2], f3 = bl[d0 + 3];
        int vyc = yy + 2;
        #pragma unroll
        for (int dy = -2; dy <= 2; ++dy) {
            #pragma unroll
            for (int dx = -2; dx <= 2; ++dx) {
                int xx = x + dx;
                if (xx < 0 || xx >= 64) continue;
                int tap = (dy + 2) * 5 + (dx + 2);
                bf16x4 vv = *(const bf16x4*)&vt[((vyc + dy) * 64 + xx) * HD + d0];
                const float* wp = &wl[tap * 32 + d0];
                f0 += (float)vv[0] * wp[0];
                f1 += (float)vv[1] * wp[1];
                f2 += (float)vv[2] * wp[2];
                f3 += (float)vv[3] * wp[3];
            }
        }
        bf16x4 ov;
        ov[0] = (bf16)(dot0 * z + f0);
        ov[1] = (bf16)(dot1 * z + f1);
        ov[2] = (bf16)(dot2 * z + f2);
        ov[3] = (bf16)(dot3 * z + f3);
        *(bf16x4*)&outp[((size_t)b * SEQ + tok) * CDIM + hh * HD + d0] = ov;
    }
}

// ---------------------------------------------------------------- K4: proj GEMM
// 1D grid of 1536 blocks; work = (b%8)*192 + b/8, mt = work/3, nt = work%3.
__global__ __launch_bounds__(256, 2)
void gemm_proj(const bf16* __restrict__ A, const bf16* __restrict__ Wb,
               const float* __restrict__ bias, float* __restrict__ out) {
    __shared__ bf16 As[128 * 64];
    __shared__ bf16 Bs[128 * 64];
    const int tid  = threadIdx.x;
    const int lane = tid & 63;
    const int wid  = tid >> 6;
    const int blk  = blockIdx.x;
    const int work = (blk & 7) * (1536 / 8) + (blk >> 3);
    const int mt   = work / 3;
    const int nt   = work - mt * 3;
    const int m0   = mt * 128;
    const int n0   = nt * 128;
    const int wm   = (wid & 1) * 64;
    const int wn   = (wid >> 1) * 64;
    const int lr   = lane & 15;
    const int lq   = lane >> 4;
    const int srow = (lane >> 3);
    const int sc   = lane & 7;

    f32x4 acc[4][4] = {};

    for (int k0 = 0; k0 < CDIM; k0 += 64) {
        #pragma unroll
        for (int it = 0; it < 4; ++it) {
            int rbase = wid * 32 + it * 8;
            int r = rbase + srow;
            int gc = sc ^ (r & 7);
            gl_lds16(&A [(size_t)(m0 + r) * CDIM + k0 + gc * 8], &As[rbase * 64]);
            gl_lds16(&Wb[(size_t)(n0 + r) * CDIM + k0 + gc * 8], &Bs[rbase * 64]);
        }
        __syncthreads();
        #pragma unroll
        for (int ks = 0; ks < 2; ++ks) {
            bf16x8 af[4], bfr[4];
            #pragma unroll
            for (int mi = 0; mi < 4; ++mi) {
                int r = wm + mi * 16 + lr;
                af[mi] = *(const bf16x8*)&As[r * 64 + ((ks * 4 + lq) ^ (r & 7)) * 8];
            }
            #pragma unroll
            for (int ni = 0; ni < 4; ++ni) {
                int r = wn + ni * 16 + lr;
                bfr[ni] = *(const bf16x8*)&Bs[r * 64 + ((ks * 4 + lq) ^ (r & 7)) * 8];
            }
            #pragma unroll
            for (int mi = 0; mi < 4; ++mi)
                #pragma unroll
                for (int ni = 0; ni < 4; ++ni)
                    acc[mi][ni] = __builtin_amdgcn_mfma_f32_16x16x32_bf16(
                        af[mi], bfr[ni], acc[mi][ni], 0, 0, 0);
        }
        __syncthreads();
    }

    #pragma unroll
    for (int mi = 0; mi < 4; ++mi) {
        #pragma unroll
        for (int ni = 0; ni < 4; ++ni) {
            int n = n0 + wn + ni * 16 + lr;
            float bv = bias[n];
            #pragma unroll
            for (int r = 0; r < 4; ++r) {
                int m = m0 + wm + mi * 16 + lq * 4 + r;
                out[(size_t)m * CDIM + n] = acc[mi][ni][r] + bv;
            }
        }
    }
}

// ---------------------------------------------------------------- launch
extern "C" void kernel_launch(void* const* d_in, const int* in_sizes, int n_in,
                              void* d_out, int out_size, void* d_ws, size_t ws_size,
                              hipStream_t stream) {
    const float* x     = (const float*)d_in[0];
    const float* qkvw  = (const float*)d_in[1];
    const float* pos   = (const float*)d_in[2];
    const float* dwcw  = (const float*)d_in[3];
    const float* dwcb  = (const float*)d_in[4];
    const float* projw = (const float*)d_in[5];
    const float* projb = (const float*)d_in[6];
    float* out = (float*)d_out;

    char* ws = (char*)d_ws;
    size_t off = 0;
    auto alloc = [&](size_t bytes) -> void* {
        void* p = ws + off;
        off += (bytes + 255) & ~(size_t)255;
        return p;
    };
    bf16* xb      = (bf16*)alloc((size_t)65536 * CDIM * 2);
    bf16* qkvw_b  = (bf16*)alloc((size_t)3 * CDIM * CDIM * 2);
    bf16* projw_b = (bf16*)alloc((size_t)CDIM * CDIM * 2);
    bf16* qh  = (bf16*)alloc((size_t)BHN * SEQ * HD * 2);
    bf16* khb = (bf16*)alloc((size_t)BHN * SEQ * HD * 2);   // reused as out_pre
    bf16* vh  = (bf16*)alloc((size_t)BHN * SEQ * HD * 2);
    float* kvb   = (float*)alloc((size_t)BHN * KVPARTS * HD * HD * 4);
    float* ksumb = (float*)alloc((size_t)BHN * KVPARTS * HD * 4);

    hipLaunchKernelGGL(convert_in, dim3(2048), dim3(256), 0, stream,
                       x, qkvw, projw, xb, qkvw_b, projw_b);
    hipLaunchKernelGGL(gemm_qkv, dim3(4608), dim3(256), 0, stream,
                       xb, qkvw_b, pos, qh, khb, vh);
    hipLaunchKernelGGL(kv_mfma, dim3(KVPARTS, BHN), dim3(256), 0, stream,
                       khb, vh, kvb, ksumb);
    bf16* outp = khb;   // kh is dead after kv_mfma; reuse as out_pre
    hipLaunchKernelGGL(attn_out, dim3(8, BHN), dim3(256), 0, stream,
                       qh, vh, kvb, ksumb, dwcw, dwcb, outp);
    hipLaunchKernelGGL(gemm_proj, dim3(1536), dim3(256), 0, stream,
                       outp, projw_b, projb, out);
}